// Round 1
// baseline (962.823 us; speedup 1.0000x reference)
//
#include <hip/hip_runtime.h>

// PrecondTiming: scatter-add arc weights to both endpoint nodes, scale by beta.
//   out[pin2node[flat_tnet2pin[2t]]]   += w[t]*beta
//   out[pin2node[flat_tnet2pin[2t+1]]] += w[t]*beta
//
// Inputs (harness order):
//   d_in[0] beta           float32 [1]
//   d_in[1] tnet_weights   float32 [NUM_TNETS]
//   d_in[2] flat_tnet2pin  int32   [2*NUM_TNETS]   (harness converts int64->int32)
//   d_in[3] pin2node_map   int32   [NUM_PINS]
// Output: float32 [NUM_NODES]

__global__ __launch_bounds__(256) void precond_timing_scatter(
    const float* __restrict__ beta,
    const float* __restrict__ tnet_weights,
    const int2* __restrict__ tnet2pin_pairs,   // flat_tnet2pin viewed as pairs
    const int*  __restrict__ pin2node_map,
    float* __restrict__ out,
    int num_tnets)
{
    int t = blockIdx.x * blockDim.x + threadIdx.x;
    if (t >= num_tnets) return;

    // coalesced 8B load of the (src,dst) pin pair for this arc
    int2 pins = tnet2pin_pairs[t];
    // fold beta in here: avoids a separate 4MB scale pass over out
    float w = tnet_weights[t] * beta[0];

    // random gathers into the 80MB pin2node table (L3-resident)
    int n0 = pin2node_map[pins.x];
    int n1 = pin2node_map[pins.y];

    // scatter-add; ~16 adds/node average, low contention
    atomicAdd(&out[n0], w);
    atomicAdd(&out[n1], w);
}

extern "C" void kernel_launch(void* const* d_in, const int* in_sizes, int n_in,
                              void* d_out, int out_size, void* d_ws, size_t ws_size,
                              hipStream_t stream) {
    const float* beta          = (const float*)d_in[0];
    const float* tnet_weights  = (const float*)d_in[1];
    const int2*  tnet2pin      = (const int2*)d_in[2];
    const int*   pin2node_map  = (const int*)d_in[3];
    float* out = (float*)d_out;

    int num_tnets = in_sizes[1];

    // harness poisons d_out with 0xAA before every call — zero it (capture-safe memset node)
    hipMemsetAsync(d_out, 0, (size_t)out_size * sizeof(float), stream);

    int block = 256;
    int grid = (num_tnets + block - 1) / block;
    precond_timing_scatter<<<grid, block, 0, stream>>>(
        beta, tnet_weights, tnet2pin, pin2node_map, out, num_tnets);
}